// Round 5
// baseline (137.551 us; speedup 1.0000x reference)
//
#include <hip/hip_runtime.h>
#include <hip/hip_fp16.h>

#define IN_DIM  16384
#define OUT_DIM 16384
#define BATCH   2048
#define NBLK    256
#define RPB     (BATCH / NBLK)   // 8 rows per block
#define TPB     1024

typedef float f32x4 __attribute__((ext_vector_type(4)));

// Two half2's per output column: ab = (c0, c1), cd = (c2, c3). 8 bytes.
struct h2x2 { __half2 ab, cd; };

// OP_COEFFS from the reference, row-major [16][4]
__device__ __constant__ float OPC[16][4] = {
    {0.f, 0.f, 0.f, 0.f}, {0.f, 0.f, 0.f, 1.f}, {0.f, 1.f, 0.f, -1.f}, {0.f, 1.f, 0.f, 0.f},
    {0.f, 0.f, 1.f, -1.f}, {0.f, 0.f, 1.f, 0.f}, {0.f, 1.f, 1.f, -2.f}, {0.f, 1.f, 1.f, -1.f},
    {1.f, -1.f, -1.f, 1.f}, {1.f, -1.f, -1.f, 2.f}, {1.f, 0.f, -1.f, 0.f}, {1.f, 0.f, -1.f, 1.f},
    {1.f, -1.f, 0.f, 0.f}, {1.f, -1.f, 0.f, 1.f}, {1.f, 0.f, 0.f, -1.f}, {1.f, 0.f, 0.f, 0.f}};

// Prep: per output column j, softmax(weights[j,0:16]) @ OP_COEFFS -> coef (f16x4),
// and pack LDS BYTE offsets: (idx_a*4) | (idx_b*4)<<16  (idx*4 < 65536).
__global__ __launch_bounds__(256) void prep_kernel(const float* __restrict__ w,
                                                   const int* __restrict__ ia,
                                                   const int* __restrict__ ib,
                                                   h2x2* __restrict__ coefh,
                                                   unsigned* __restrict__ packed) {
    int j = blockIdx.x * 256 + threadIdx.x;
    if (j >= OUT_DIM) return;

    const float4* wr = (const float4*)(w + (size_t)j * 16);
    float wv[16];
    float4 w0 = wr[0], w1 = wr[1], w2 = wr[2], w3 = wr[3];
    wv[0] = w0.x; wv[1] = w0.y; wv[2] = w0.z; wv[3] = w0.w;
    wv[4] = w1.x; wv[5] = w1.y; wv[6] = w1.z; wv[7] = w1.w;
    wv[8] = w2.x; wv[9] = w2.y; wv[10] = w2.z; wv[11] = w2.w;
    wv[12] = w3.x; wv[13] = w3.y; wv[14] = w3.z; wv[15] = w3.w;

    float m = wv[0];
#pragma unroll
    for (int k = 1; k < 16; ++k) m = fmaxf(m, wv[k]);
    float s = 0.f;
#pragma unroll
    for (int k = 0; k < 16; ++k) { wv[k] = expf(wv[k] - m); s += wv[k]; }
    float inv = 1.f / s;

    float c0 = 0.f, c1 = 0.f, c2 = 0.f, c3 = 0.f;
#pragma unroll
    for (int k = 0; k < 16; ++k) {
        float p = wv[k];
        c0 = fmaf(p, OPC[k][0], c0);
        c1 = fmaf(p, OPC[k][1], c1);
        c2 = fmaf(p, OPC[k][2], c2);
        c3 = fmaf(p, OPC[k][3], c3);
    }
    h2x2 c;
    c.ab = __floats2half2_rn(c0 * inv, c1 * inv);
    c.cd = __floats2half2_rn(c2 * inv, c3 * inv);
    coefh[j] = c;
    packed[j] = ((unsigned)ia[j] << 2) | ((unsigned)ib[j] << 18);
}

// One block owns 8 rows. coef/packed are row-invariant per thread -> hoisted into
// registers once (f16 coef: 48 VGPR total hoist). Inner loop has ZERO VMEM loads.
// __launch_bounds__(1024,4): block is 1/CU (128 KiB LDS) = 4 waves/SIMD, so cap
// VGPR at 128 and stop the allocator's 8-wave heuristic that spilled round 4.
__global__ __launch_bounds__(TPB, 4) void logic_kernel(const float* __restrict__ x,
                                                       const unsigned* __restrict__ packed,
                                                       const h2x2* __restrict__ coefh,
                                                       float* __restrict__ out) {
    __shared__ float lds[2][IN_DIM];  // 128 KiB -> 1 block/CU

    const int tid = threadIdx.x;
    const int row0 = blockIdx.x * RPB;

    // Hoist per-thread coef/packed (same output columns for every row).
    uint4 pk[4];
    h2x2 cf[4][4];
#pragma unroll
    for (int it = 0; it < 4; ++it) {
        const int j0 = (it * TPB + tid) * 4;
        pk[it] = *(const uint4*)(packed + j0);
        cf[it][0] = coefh[j0 + 0];
        cf[it][1] = coefh[j0 + 1];
        cf[it][2] = coefh[j0 + 2];
        cf[it][3] = coefh[j0 + 3];
    }

    // Prologue: stage row0 into lds[0]
    {
        const float4* src = (const float4*)(x + (size_t)row0 * IN_DIM);
        float4* dst = (float4*)lds[0];
#pragma unroll
        for (int k = 0; k < 4; ++k)
            dst[k * TPB + tid] = src[k * TPB + tid];
    }

    for (int r = 0; r < RPB; ++r) {
        const int cur = r & 1;
        __syncthreads();  // lgkm drain: lds[cur] staged; all waves done with lds[cur^1]

        const bool pf = (r + 1 < RPB);
        float4 t0 = {}, t1 = {}, t2 = {}, t3 = {};
        if (pf) {
            const float4* src = (const float4*)(x + (size_t)(row0 + r + 1) * IN_DIM);
            t0 = src[0 * TPB + tid];
            t1 = src[1 * TPB + tid];
            t2 = src[2 * TPB + tid];
            t3 = src[3 * TPB + tid];
        }
        __builtin_amdgcn_sched_barrier(0);  // pin prefetch load issue before compute

        const char* buf = (const char*)lds[cur];
        float* outr = out + (size_t)(row0 + r) * IN_DIM;

#pragma unroll
        for (int it = 0; it < 4; ++it) {
            const int j0 = (it * TPB + tid) * 4;
            const uint4 pi = pk[it];

            f32x4 o;
            {
                float a = *(const float*)(buf + (pi.x & 0xFFFFu));
                float b = *(const float*)(buf + (pi.x >> 16));
                float c0 = __low2float(cf[it][0].ab), c1 = __high2float(cf[it][0].ab);
                float c2 = __low2float(cf[it][0].cd), c3 = __high2float(cf[it][0].cd);
                o.x = fmaf(a, fmaf(c3, b, c1), fmaf(c2, b, c0));
            }
            {
                float a = *(const float*)(buf + (pi.y & 0xFFFFu));
                float b = *(const float*)(buf + (pi.y >> 16));
                float c0 = __low2float(cf[it][1].ab), c1 = __high2float(cf[it][1].ab);
                float c2 = __low2float(cf[it][1].cd), c3 = __high2float(cf[it][1].cd);
                o.y = fmaf(a, fmaf(c3, b, c1), fmaf(c2, b, c0));
            }
            {
                float a = *(const float*)(buf + (pi.z & 0xFFFFu));
                float b = *(const float*)(buf + (pi.z >> 16));
                float c0 = __low2float(cf[it][2].ab), c1 = __high2float(cf[it][2].ab);
                float c2 = __low2float(cf[it][2].cd), c3 = __high2float(cf[it][2].cd);
                o.z = fmaf(a, fmaf(c3, b, c1), fmaf(c2, b, c0));
            }
            {
                float a = *(const float*)(buf + (pi.w & 0xFFFFu));
                float b = *(const float*)(buf + (pi.w >> 16));
                float c0 = __low2float(cf[it][3].ab), c1 = __high2float(cf[it][3].ab);
                float c2 = __low2float(cf[it][3].cd), c3 = __high2float(cf[it][3].cd);
                o.w = fmaf(a, fmaf(c3, b, c1), fmaf(c2, b, c0));
            }
            *(f32x4*)(outr + j0) = o;
        }

        if (pf) {
            float4* dst = (float4*)lds[cur ^ 1];
            dst[0 * TPB + tid] = t0;
            dst[1 * TPB + tid] = t1;
            dst[2 * TPB + tid] = t2;
            dst[3 * TPB + tid] = t3;
        }
    }
}

extern "C" void kernel_launch(void* const* d_in, const int* in_sizes, int n_in,
                              void* d_out, int out_size, void* d_ws, size_t ws_size,
                              hipStream_t stream) {
    const float* x = (const float*)d_in[0];
    const int* ia = (const int*)d_in[1];
    const int* ib = (const int*)d_in[2];
    const float* w = (const float*)d_in[3];
    float* out = (float*)d_out;

    // ws layout: [0, 128 KiB) coefh h2x2[OUT_DIM]; [128 KiB, 192 KiB) packed u32[OUT_DIM]
    h2x2* coefh = (h2x2*)d_ws;
    unsigned* packed = (unsigned*)((char*)d_ws + (size_t)OUT_DIM * sizeof(h2x2));

    prep_kernel<<<OUT_DIM / 256, 256, 0, stream>>>(w, ia, ib, coefh, packed);
    logic_kernel<<<NBLK, TPB, 0, stream>>>(x, packed, coefh, out);
}

// Round 6
// 76.530 us; speedup vs baseline: 1.7973x; 1.7973x over previous
//
#include <hip/hip_runtime.h>
#include <hip/hip_fp16.h>

#define IN_DIM  16384
#define OUT_DIM 16384
#define BATCH   2048
#define NBLK    256
#define RPB     (BATCH / NBLK)   // 8 rows per block
#define TPB     512
#define ITS     (OUT_DIM / (TPB * 4))   // 8 j-iterations per row
#define STG     (IN_DIM / (TPB * 4))    // 8 float4 stage loads per thread

typedef float f32x4 __attribute__((ext_vector_type(4)));

// Two half2's per output column: ab = (c0, c1), cd = (c2, c3). 8 bytes.
struct h2x2 { __half2 ab, cd; };

// OP_COEFFS from the reference, row-major [16][4]
__device__ __constant__ float OPC[16][4] = {
    {0.f, 0.f, 0.f, 0.f}, {0.f, 0.f, 0.f, 1.f}, {0.f, 1.f, 0.f, -1.f}, {0.f, 1.f, 0.f, 0.f},
    {0.f, 0.f, 1.f, -1.f}, {0.f, 0.f, 1.f, 0.f}, {0.f, 1.f, 1.f, -2.f}, {0.f, 1.f, 1.f, -1.f},
    {1.f, -1.f, -1.f, 1.f}, {1.f, -1.f, -1.f, 2.f}, {1.f, 0.f, -1.f, 0.f}, {1.f, 0.f, -1.f, 1.f},
    {1.f, -1.f, 0.f, 0.f}, {1.f, -1.f, 0.f, 1.f}, {1.f, 0.f, 0.f, -1.f}, {1.f, 0.f, 0.f, 0.f}};

// Prep: per output column j, softmax(weights[j,0:16]) @ OP_COEFFS -> coef (f16x4),
// and pack LDS BYTE offsets: (idx_a*4) | (idx_b*4)<<16.
__global__ __launch_bounds__(256) void prep_kernel(const float* __restrict__ w,
                                                   const int* __restrict__ ia,
                                                   const int* __restrict__ ib,
                                                   h2x2* __restrict__ coefh,
                                                   unsigned* __restrict__ packed) {
    int j = blockIdx.x * 256 + threadIdx.x;
    if (j >= OUT_DIM) return;

    const float4* wr = (const float4*)(w + (size_t)j * 16);
    float wv[16];
    float4 w0 = wr[0], w1 = wr[1], w2 = wr[2], w3 = wr[3];
    wv[0] = w0.x; wv[1] = w0.y; wv[2] = w0.z; wv[3] = w0.w;
    wv[4] = w1.x; wv[5] = w1.y; wv[6] = w1.z; wv[7] = w1.w;
    wv[8] = w2.x; wv[9] = w2.y; wv[10] = w2.z; wv[11] = w2.w;
    wv[12] = w3.x; wv[13] = w3.y; wv[14] = w3.z; wv[15] = w3.w;

    float m = wv[0];
#pragma unroll
    for (int k = 1; k < 16; ++k) m = fmaxf(m, wv[k]);
    float s = 0.f;
#pragma unroll
    for (int k = 0; k < 16; ++k) { wv[k] = expf(wv[k] - m); s += wv[k]; }
    float inv = 1.f / s;

    float c0 = 0.f, c1 = 0.f, c2 = 0.f, c3 = 0.f;
#pragma unroll
    for (int k = 0; k < 16; ++k) {
        float p = wv[k];
        c0 = fmaf(p, OPC[k][0], c0);
        c1 = fmaf(p, OPC[k][1], c1);
        c2 = fmaf(p, OPC[k][2], c2);
        c3 = fmaf(p, OPC[k][3], c3);
    }
    h2x2 c;
    c.ab = __floats2half2_rn(c0 * inv, c1 * inv);
    c.cd = __floats2half2_rn(c2 * inv, c3 * inv);
    coefh[j] = c;
    packed[j] = ((unsigned)ia[j] << 2) | ((unsigned)ib[j] << 18);
}

// 512-thread block (dodges the 64-VGPR wall seen at 1024), 1 block/CU,
// 2x64KiB double buffer. coef/packed hoisted into registers once per block
// (row-invariant): inner loop has ZERO VMEM loads. T14 async-STAGE split:
// issue row r+1 global loads before compute(r), ds_write after.
__global__ __launch_bounds__(TPB, 2) void logic_kernel(const float* __restrict__ x,
                                                       const unsigned* __restrict__ packed,
                                                       const h2x2* __restrict__ coefh,
                                                       float* __restrict__ out) {
    __shared__ float lds[2][IN_DIM];  // 128 KiB -> 1 block/CU (8 waves)

    const int tid = threadIdx.x;
    const int row0 = blockIdx.x * RPB;

    // Hoist per-thread coef/packed (same output columns for every row).
    uint4 pk[ITS];      // 32 VGPRs
    h2x2 cf[ITS][4];    // 64 VGPRs (f16 coef)
#pragma unroll
    for (int it = 0; it < ITS; ++it) {
        const int j0 = (it * TPB + tid) * 4;
        pk[it] = *(const uint4*)(packed + j0);
        cf[it][0] = coefh[j0 + 0];
        cf[it][1] = coefh[j0 + 1];
        cf[it][2] = coefh[j0 + 2];
        cf[it][3] = coefh[j0 + 3];
    }

    // Prologue: stage row0 into lds[0]
    {
        const float4* src = (const float4*)(x + (size_t)row0 * IN_DIM);
        float4* dst = (float4*)lds[0];
#pragma unroll
        for (int k = 0; k < STG; ++k)
            dst[k * TPB + tid] = src[k * TPB + tid];
    }

    for (int r = 0; r < RPB; ++r) {
        const int cur = r & 1;
        __syncthreads();  // lgkm drain: lds[cur] staged; all waves done with lds[cur^1]

        const bool pf = (r + 1 < RPB);
        float4 t[STG];
#pragma unroll
        for (int k = 0; k < STG; ++k) t[k] = make_float4(0.f, 0.f, 0.f, 0.f);
        if (pf) {
            const float4* src = (const float4*)(x + (size_t)(row0 + r + 1) * IN_DIM);
#pragma unroll
            for (int k = 0; k < STG; ++k)
                t[k] = src[k * TPB + tid];
        }
        __builtin_amdgcn_sched_barrier(0);  // pin prefetch load issue before compute

        const char* buf = (const char*)lds[cur];
        float* outr = out + (size_t)(row0 + r) * IN_DIM;

#pragma unroll
        for (int it = 0; it < ITS; ++it) {
            const int j0 = (it * TPB + tid) * 4;
            const uint4 pi = pk[it];

            f32x4 o;
            {
                float a = *(const float*)(buf + (pi.x & 0xFFFFu));
                float b = *(const float*)(buf + (pi.x >> 16));
                float c0 = __low2float(cf[it][0].ab), c1 = __high2float(cf[it][0].ab);
                float c2 = __low2float(cf[it][0].cd), c3 = __high2float(cf[it][0].cd);
                o.x = fmaf(a, fmaf(c3, b, c1), fmaf(c2, b, c0));
            }
            {
                float a = *(const float*)(buf + (pi.y & 0xFFFFu));
                float b = *(const float*)(buf + (pi.y >> 16));
                float c0 = __low2float(cf[it][1].ab), c1 = __high2float(cf[it][1].ab);
                float c2 = __low2float(cf[it][1].cd), c3 = __high2float(cf[it][1].cd);
                o.y = fmaf(a, fmaf(c3, b, c1), fmaf(c2, b, c0));
            }
            {
                float a = *(const float*)(buf + (pi.z & 0xFFFFu));
                float b = *(const float*)(buf + (pi.z >> 16));
                float c0 = __low2float(cf[it][2].ab), c1 = __high2float(cf[it][2].ab);
                float c2 = __low2float(cf[it][2].cd), c3 = __high2float(cf[it][2].cd);
                o.z = fmaf(a, fmaf(c3, b, c1), fmaf(c2, b, c0));
            }
            {
                float a = *(const float*)(buf + (pi.w & 0xFFFFu));
                float b = *(const float*)(buf + (pi.w >> 16));
                float c0 = __low2float(cf[it][3].ab), c1 = __high2float(cf[it][3].ab);
                float c2 = __low2float(cf[it][3].cd), c3 = __high2float(cf[it][3].cd);
                o.w = fmaf(a, fmaf(c3, b, c1), fmaf(c2, b, c0));
            }
            *(f32x4*)(outr + j0) = o;
        }

        if (pf) {
            float4* dst = (float4*)lds[cur ^ 1];
#pragma unroll
            for (int k = 0; k < STG; ++k)
                dst[k * TPB + tid] = t[k];
        }
    }
}

extern "C" void kernel_launch(void* const* d_in, const int* in_sizes, int n_in,
                              void* d_out, int out_size, void* d_ws, size_t ws_size,
                              hipStream_t stream) {
    const float* x = (const float*)d_in[0];
    const int* ia = (const int*)d_in[1];
    const int* ib = (const int*)d_in[2];
    const float* w = (const float*)d_in[3];
    float* out = (float*)d_out;

    // ws layout: [0, 128 KiB) coefh h2x2[OUT_DIM]; [128 KiB, 192 KiB) packed u32[OUT_DIM]
    h2x2* coefh = (h2x2*)d_ws;
    unsigned* packed = (unsigned*)((char*)d_ws + (size_t)OUT_DIM * sizeof(h2x2));

    prep_kernel<<<OUT_DIM / 256, 256, 0, stream>>>(w, ia, ib, coefh, packed);
    logic_kernel<<<NBLK, TPB, 0, stream>>>(x, packed, coefh, out);
}